// Round 7
// baseline (379.252 us; speedup 1.0000x reference)
//
#include <hip/hip_runtime.h>
#include <hip/hip_bf16.h>
#include <math.h>

typedef __attribute__((ext_vector_type(4))) float f32x4;
typedef __attribute__((ext_vector_type(8))) short bf16x8;

#define T_TOK 2048
#define H_DIM 1024
#define I_DIM 2048
#define E_NUM 8

// RNE float -> bf16
__device__ inline unsigned short f2bf(float f) {
  union { float f; unsigned int u; } v; v.f = f;
  unsigned int r = v.u + 0x7fffu + ((v.u >> 16) & 1u);
  return (unsigned short)(r >> 16);
}
__device__ inline unsigned int pack2(float a, float b) {
  return (unsigned int)f2bf(a) | ((unsigned int)f2bf(b) << 16);
}

// async global->LDS, 16 bytes per lane
__device__ inline void gld16(const void* g, void* l) {
  __builtin_amdgcn_global_load_lds((const __attribute__((address_space(1))) void*)g,
                                   (__attribute__((address_space(3))) void*)l, 16, 0, 0);
}

// ---------------- paired 64x64 fp32 [R][C] -> bf16 [C][R] transpose ----------------
// rows [rp*128, rp*128+128) x cols [ct*64, ct*64+64); 8 float4 loads up-front;
// LDS [c][r] stride 66 shorts (measured 0 bank conflicts); 128B-contiguous stores.
__device__ inline void transpose_pair(const float* __restrict__ ip, unsigned short* __restrict__ op,
                                      int R, int C, int rp, int ct, char* smem)
{
  unsigned short (*tl)[66] = (unsigned short (*)[66])smem;
  int r0 = rp * 128, c0 = ct * 64;
  int tid = threadIdx.x;
  int rq = (tid >> 4) * 4;
  int c4 = (tid & 15) * 4;
  const float* b0 = ip + (size_t)(r0 + rq) * C + c0 + c4;
  const float* b1 = b0 + (size_t)64 * C;
  float4 v[8];
  v[0] = *(const float4*)(b0);
  v[1] = *(const float4*)(b0 + C);
  v[2] = *(const float4*)(b0 + 2 * C);
  v[3] = *(const float4*)(b0 + 3 * C);
  v[4] = *(const float4*)(b1);
  v[5] = *(const float4*)(b1 + C);
  v[6] = *(const float4*)(b1 + 2 * C);
  v[7] = *(const float4*)(b1 + 3 * C);
  const float* f = (const float*)v;
#pragma unroll
  for (int j = 0; j < 4; ++j) {
    *(unsigned int*)&tl[c4 + j][rq]          = pack2(f[0 * 4 + j], f[1 * 4 + j]);
    *(unsigned int*)&tl[c4 + j][rq + 2]      = pack2(f[2 * 4 + j], f[3 * 4 + j]);
    *(unsigned int*)&tl[64 + c4 + j][rq]     = pack2(f[4 * 4 + j], f[5 * 4 + j]);
    *(unsigned int*)&tl[64 + c4 + j][rq + 2] = pack2(f[6 * 4 + j], f[7 * 4 + j]);
  }
  __syncthreads();
  int c = tid >> 3, r8 = (tid & 7) * 8;
#pragma unroll
  for (int it = 0; it < 2; ++it) {
    int cc = c + it * 32;
#pragma unroll
    for (int p = 0; p < 2; ++p) {
      uint4 o;
      o.x = *(const unsigned int*)&tl[p * 64 + cc][r8];
      o.y = *(const unsigned int*)&tl[p * 64 + cc][r8 + 2];
      o.z = *(const unsigned int*)&tl[p * 64 + cc][r8 + 4];
      o.w = *(const unsigned int*)&tl[p * 64 + cc][r8 + 6];
      *(uint4*)(op + (size_t)(c0 + cc) * R + r0 + p * 64 + r8) = o;
    }
  }
}

// ---------------- kernel 1: w1/w3 transpose with gate interleaved (every 9th block) ----------------
// grid 4608: bx%9==8 -> gate block (512), else transpose (4096)
__global__ __launch_bounds__(256) void gate_t13(
    const float* __restrict__ x, const float* __restrict__ gw, const float* __restrict__ gb,
    int* __restrict__ rec_e, float* __restrict__ rec_w, unsigned short* __restrict__ xb,
    const float* __restrict__ w1, const float* __restrict__ w3,
    unsigned short* __restrict__ w1t, unsigned short* __restrict__ w3t)
{
  __shared__ __align__(16) char smem[128 * 66 * 2];
  int bx = blockIdx.x;
  if (bx % 9 != 8) {
    int t = bx - bx / 9;       // 0..4095
    int m = t >> 8;            // 0..15
    int t8 = t & 255;
    int rp = t8 & 7;           // R = H_DIM -> 8 row-pairs
    int ct = t8 >> 3;          // C = I_DIM -> 32 col tiles
    const float* ip = (m < 8 ? w1 : w3) + (size_t)(m & 7) * ((size_t)H_DIM * I_DIM);
    unsigned short* op = (m < 8 ? w1t : w3t) + (size_t)(m & 7) * ((size_t)H_DIM * I_DIM);
    transpose_pair(ip, op, H_DIM, I_DIM, rp, ct, smem);
    return;
  }
  int gblk = bx / 9;           // 0..511
  int wv = threadIdx.x >> 6, lane = threadIdx.x & 63;
  int t = gblk * 4 + wv;
  const float* xr = x + (size_t)t * H_DIM;
  unsigned short* xo = xb + (size_t)t * H_DIM;
  float acc[8];
#pragma unroll
  for (int e = 0; e < 8; ++e) acc[e] = 0.f;
  for (int i = 0; i < H_DIM / 64; ++i) {
    int h = i * 64 + lane;
    float xv = xr[h];
    xo[h] = f2bf(xv);
    const float4* g = (const float4*)(gw + (size_t)h * 8);
    float4 g0 = g[0], g1 = g[1];
    acc[0] += xv * g0.x; acc[1] += xv * g0.y; acc[2] += xv * g0.z; acc[3] += xv * g0.w;
    acc[4] += xv * g1.x; acc[5] += xv * g1.y; acc[6] += xv * g1.z; acc[7] += xv * g1.w;
  }
#pragma unroll
  for (int s = 1; s < 64; s <<= 1) {
#pragma unroll
    for (int e = 0; e < 8; ++e) acc[e] += __shfl_xor(acc[e], s);
  }
  if (lane == 0) {
    float l[8];
#pragma unroll
    for (int e = 0; e < 8; ++e) l[e] = acc[e] + gb[e];
    int e0 = 0;
    for (int e = 1; e < 8; ++e) if (l[e] > l[e0]) e0 = e;
    int e1 = (e0 == 0) ? 1 : 0;
    for (int e = 0; e < 8; ++e) if (e != e0 && l[e] > l[e1]) e1 = e;
    float w0 = 1.f / (1.f + expf(l[e1] - l[e0]));
    rec_e[t * 2]     = e0; rec_e[t * 2 + 1] = e1;
    rec_w[t * 2]     = w0; rec_w[t * 2 + 1] = 1.f - w0;
  }
}

// ---------------- routing: 8 blocks, one per expert ----------------
__global__ __launch_bounds__(256) void route8(
    const int* __restrict__ rec_e, const float* __restrict__ rec_w,
    int* __restrict__ counts_g, int* __restrict__ list_tok, float* __restrict__ list_w)
{
  __shared__ int cnt[8];
  __shared__ int fill;
  int e = blockIdx.x;
  int tid = threadIdx.x;
  if (tid < 8) cnt[tid] = 0;
  if (tid == 0) fill = 0;
  __syncthreads();
  int e_loc[16];
  int c_loc[8];
#pragma unroll
  for (int k = 0; k < 8; ++k) c_loc[k] = 0;
#pragma unroll
  for (int it = 0; it < 16; ++it) {
    e_loc[it] = rec_e[it * 256 + tid] & 7;
    c_loc[e_loc[it]]++;
  }
#pragma unroll
  for (int k = 0; k < 8; ++k) if (c_loc[k]) atomicAdd(&cnt[k], c_loc[k]);
  __syncthreads();
  if (e == 0 && tid < 8) counts_g[tid] = cnt[tid];
  int base = 0;
#pragma unroll
  for (int k = 0; k < 8; ++k) if (k < e) base += cnt[k];
#pragma unroll
  for (int it = 0; it < 16; ++it) {
    if (e_loc[it] == e) {
      int i = it * 256 + tid;
      int pos = atomicAdd(&fill, 1);
      list_tok[base + pos] = i;            // i = (t<<1)|k
      list_w[base + pos]   = rec_w[i];
    }
  }
}

// ---------------- kernel 3: gemm1 (128x128, BK=32, dual) interleaved 1:1 with w2 transpose ----------------
// grid 4096: bx even -> transpose tile bx/2 (2048); bx odd -> gemm block bx/2 (2048, ~512 live)
__global__ __launch_bounds__(256, 2) void gemm1_t2(
    const unsigned short* __restrict__ xb,
    const unsigned short* __restrict__ w1t,
    const unsigned short* __restrict__ w3t,
    const int* __restrict__ counts,
    const int* __restrict__ list_tok,
    unsigned short* __restrict__ hbuf,
    const float* __restrict__ w2,
    unsigned short* __restrict__ w2t)
{
  __shared__ __align__(16) char smem[24576];
  int bx = blockIdx.x;
  if ((bx & 1) == 0) {
    int t = bx >> 1;           // 0..2047
    int e = t >> 8;            // 0..7
    int t8 = t & 255;
    int rp = t8 & 15;          // R = I_DIM -> 16 row-pairs
    int ct = t8 >> 4;          // C = H_DIM -> 16 col tiles
    const float* ip = w2 + (size_t)e * ((size_t)H_DIM * I_DIM);
    unsigned short* op = w2t + (size_t)e * ((size_t)H_DIM * I_DIM);
    transpose_pair(ip, op, I_DIM, H_DIM, rp, ct, smem);
    return;
  }
  int g = bx >> 1;             // 0..2047
  int e = g >> 8;
  int y = (g >> 4) & 15;
  int ix = g & 15;
  int nbase = 0;
#pragma unroll
  for (int i = 0; i < 8; ++i) if (i < e) nbase += counts[i];
  int n_e = counts[e];
  int t0 = y * 128;
  if (t0 >= n_e) return;
  int i0 = ix * 128;

  unsigned short* As  = (unsigned short*)smem;            // 128*32 = 8KB
  unsigned short* B1s = (unsigned short*)(smem + 8192);   // 8KB
  unsigned short* B3s = (unsigned short*)(smem + 16384);  // 8KB

  int tid = threadIdx.x;
  int r4 = tid >> 2;
  int seg = (tid & 3) * 8;

  int sr0 = t0 + r4;       if (sr0 >= n_e) sr0 = n_e - 1;
  int sr1 = t0 + 64 + r4;  if (sr1 >= n_e) sr1 = n_e - 1;
  int tok0 = list_tok[nbase + sr0] >> 1;
  int tok1 = list_tok[nbase + sr1] >> 1;
  const char* gA0 = (const char*)(xb + (size_t)tok0 * H_DIM + seg);
  const char* gA1 = (const char*)(xb + (size_t)tok1 * H_DIM + seg);
  const char* gB1a = (const char*)(w1t + ((size_t)e * I_DIM + i0 + r4) * H_DIM + seg);
  const char* gB1b = (const char*)(w1t + ((size_t)e * I_DIM + i0 + 64 + r4) * H_DIM + seg);
  const char* gB3a = (const char*)(w3t + ((size_t)e * I_DIM + i0 + r4) * H_DIM + seg);
  const char* gB3b = (const char*)(w3t + ((size_t)e * I_DIM + i0 + 64 + r4) * H_DIM + seg);

  char* lA0  = (char*)As + tid * 16;
  char* lA1  = (char*)As + 4096 + tid * 16;
  char* lB1a = (char*)B1s + tid * 16;
  char* lB1b = (char*)B1s + 4096 + tid * 16;
  char* lB3a = (char*)B3s + tid * 16;
  char* lB3b = (char*)B3s + 4096 + tid * 16;

  int w = tid >> 6, lane = tid & 63, lm = lane & 15, lq = lane >> 4;
  int wm = w & 1, wn = w >> 1;   // m-off wm*64, n-off wn*64

  f32x4 acc1[4][4], acc3[4][4];
#pragma unroll
  for (int i = 0; i < 4; ++i)
#pragma unroll
    for (int j = 0; j < 4; ++j) { acc1[i][j] = (f32x4){0,0,0,0}; acc3[i][j] = (f32x4){0,0,0,0}; }

  for (int kb = 0; kb < H_DIM; kb += 32) {
    __syncthreads();
    gld16(gA0 + kb * 2, lA0);
    gld16(gA1 + kb * 2, lA1);
    gld16(gB1a + kb * 2, lB1a);
    gld16(gB1b + kb * 2, lB1b);
    gld16(gB3a + kb * 2, lB3a);
    gld16(gB3b + kb * 2, lB3b);
    __syncthreads();
    bf16x8 a[4], b1[4], b3[4];
#pragma unroll
    for (int i = 0; i < 4; ++i)
      a[i] = *(const bf16x8*)((const char*)As + 2 * ((wm * 64 + i * 16 + lm) * 32 + lq * 8));
#pragma unroll
    for (int j = 0; j < 4; ++j) {
      b1[j] = *(const bf16x8*)((const char*)B1s + 2 * ((wn * 64 + j * 16 + lm) * 32 + lq * 8));
      b3[j] = *(const bf16x8*)((const char*)B3s + 2 * ((wn * 64 + j * 16 + lm) * 32 + lq * 8));
    }
#pragma unroll
    for (int i = 0; i < 4; ++i)
#pragma unroll
      for (int j = 0; j < 4; ++j) {
        acc1[i][j] = __builtin_amdgcn_mfma_f32_16x16x32_bf16(a[i], b1[j], acc1[i][j], 0, 0, 0);
        acc3[i][j] = __builtin_amdgcn_mfma_f32_16x16x32_bf16(a[i], b3[j], acc3[i][j], 0, 0, 0);
      }
  }

#pragma unroll
  for (int i = 0; i < 4; ++i) {
#pragma unroll
    for (int rr = 0; rr < 4; ++rr) {
      int slot = t0 + wm * 64 + i * 16 + lq * 4 + rr;
      if (slot < n_e) {
        unsigned short* orow = hbuf + (size_t)(nbase + slot) * I_DIM + i0 + wn * 64 + lm;
#pragma unroll
        for (int j = 0; j < 4; ++j) {
          float gg = acc1[i][j][rr], u = acc3[i][j][rr];
          float hv = (gg / (1.f + __expf(-gg))) * u;
          orow[j * 16] = f2bf(hv);
        }
      }
    }
  }
}

// ---------------- GEMM2: 128 slots x 128 H, BK=64, split-K=4, 8-plane partial ----------------
__global__ __launch_bounds__(256, 2) void gemm2(
    const unsigned short* __restrict__ hbuf,
    const unsigned short* __restrict__ w2t,
    const int* __restrict__ counts,
    const int* __restrict__ list_tok,
    const float* __restrict__ list_w,
    float* __restrict__ partial)
{
  __shared__ __align__(16) char smem[32768];
  int e = blockIdx.z;
  int nbase = 0;
#pragma unroll
  for (int i = 0; i < 8; ++i) if (i < e) nbase += counts[i];
  int n_e = counts[e];
  int ts = blockIdx.y >> 2, kh = blockIdx.y & 3;
  int t0 = ts * 128;
  if (t0 >= n_e) return;
  int h0 = blockIdx.x * 128;
  int k0 = kh * (I_DIM / 4);   // 512-wide K chunk

  char* As = smem;             // 2 panels x 8KB (128 rows x 64B)
  char* Bs = smem + 16384;     // 2 panels x 8KB

  int tid = threadIdx.x;
  int r2 = tid >> 2;
  int seg = (tid & 3) * 8;

  int sr0 = t0 + r2;       if (sr0 >= n_e) sr0 = n_e - 1;
  int sr1 = t0 + 64 + r2;  if (sr1 >= n_e) sr1 = n_e - 1;
  const char* gA0 = (const char*)(hbuf + (size_t)(nbase + sr0) * I_DIM + k0 + seg);
  const char* gA1 = (const char*)(hbuf + (size_t)(nbase + sr1) * I_DIM + k0 + seg);
  const char* gB0 = (const char*)(w2t + ((size_t)e * H_DIM + h0 + r2) * I_DIM + k0 + seg);
  const char* gB1 = (const char*)(w2t + ((size_t)e * H_DIM + h0 + 64 + r2) * I_DIM + k0 + seg);

  int w = tid >> 6, lane = tid & 63, lm = lane & 15, lq = lane >> 4;
  int wm = w & 1, wn = w >> 1;

  f32x4 acc[4][4];
#pragma unroll
  for (int i = 0; i < 4; ++i)
#pragma unroll
    for (int j = 0; j < 4; ++j) acc[i][j] = (f32x4){0,0,0,0};

  for (int kb = 0; kb < I_DIM / 4; kb += 64) {
    __syncthreads();
    gld16(gA0 + kb * 2,       As + tid * 16);
    gld16(gA1 + kb * 2,       As + 4096 + tid * 16);
    gld16(gA0 + kb * 2 + 64,  As + 8192 + tid * 16);
    gld16(gA1 + kb * 2 + 64,  As + 12288 + tid * 16);
    gld16(gB0 + kb * 2,       Bs + tid * 16);
    gld16(gB1 + kb * 2,       Bs + 4096 + tid * 16);
    gld16(gB0 + kb * 2 + 64,  Bs + 8192 + tid * 16);
    gld16(gB1 + kb * 2 + 64,  Bs + 12288 + tid * 16);
    __syncthreads();
#pragma unroll
    for (int s = 0; s < 2; ++s) {
      bf16x8 a[4], b[4];
#pragma unroll
      for (int i = 0; i < 4; ++i)
        a[i] = *(const bf16x8*)(As + s * 8192 + ((wm * 64 + i * 16 + lm) * 32 + lq * 8) * 2);
#pragma unroll
      for (int j = 0; j < 4; ++j)
        b[j] = *(const bf16x8*)(Bs + s * 8192 + ((wn * 64 + j * 16 + lm) * 32 + lq * 8) * 2);
#pragma unroll
      for (int i = 0; i < 4; ++i)
#pragma unroll
        for (int j = 0; j < 4; ++j)
          acc[i][j] = __builtin_amdgcn_mfma_f32_16x16x32_bf16(a[i], b[j], acc[i][j], 0, 0, 0);
    }
  }

  int entv[4][4]; float wtv[4][4];
#pragma unroll
  for (int i = 0; i < 4; ++i)
#pragma unroll
    for (int rr = 0; rr < 4; ++rr) {
      int slot = t0 + wm * 64 + i * 16 + lq * 4 + rr;
      if (slot < n_e) { entv[i][rr] = list_tok[nbase + slot]; wtv[i][rr] = list_w[nbase + slot]; }
      else entv[i][rr] = -1;
    }
#pragma unroll
  for (int i = 0; i < 4; ++i)
#pragma unroll
    for (int j = 0; j < 4; ++j)
#pragma unroll
      for (int rr = 0; rr < 4; ++rr) {
        if (entv[i][rr] >= 0) {
          int t = entv[i][rr] >> 1, kk = entv[i][rr] & 1;
          int plane = kh * 2 + kk;
          partial[((size_t)plane * T_TOK + t) * H_DIM + h0 + wn * 64 + j * 16 + lm] =
              acc[i][j][rr] * wtv[i][rr];
        }
      }
}

// ---------------- out = sum of 8 partial planes ----------------
__global__ __launch_bounds__(256) void combine8(const float* __restrict__ partial,
                                                float* __restrict__ out)
{
  const size_t P = (size_t)T_TOK * H_DIM;
  size_t i = (size_t)(blockIdx.x * 256 + threadIdx.x) * 4;
  float4 s = *(const float4*)(partial + i);
#pragma unroll
  for (int p = 1; p < 8; ++p) {
    float4 v = *(const float4*)(partial + p * P + i);
    s.x += v.x; s.y += v.y; s.z += v.z; s.w += v.w;
  }
  *(float4*)(out + i) = s;
}

extern "C" void kernel_launch(void* const* d_in, const int* in_sizes, int n_in,
                              void* d_out, int out_size, void* d_ws, size_t ws_size,
                              hipStream_t stream) {
  const float* x  = (const float*)d_in[0];
  const float* gw = (const float*)d_in[1];
  const float* gb = (const float*)d_in[2];
  const float* w1 = (const float*)d_in[3];
  const float* w3 = (const float*)d_in[4];
  const float* w2 = (const float*)d_in[5];
  float* out = (float*)d_out;

  char* ws = (char*)d_ws;
  int*   counts   = (int*)(ws);            // 8 ints
  int*   rec_e    = (int*)(ws + 128);      // 4096 ints
  float* rec_w    = (float*)(ws + 16512);  // 4096 floats
  int*   list_tok = (int*)(ws + 32896);    // 4096 ints
  float* list_w   = (float*)(ws + 49280);  // 4096 floats
  const size_t MB = 1024ull * 1024ull;
  unsigned short* xb   = (unsigned short*)(ws + 1 * MB);    // 4 MB
  unsigned short* w1t  = (unsigned short*)(ws + 5 * MB);    // 32 MB  [E][I][H]
  float* partial       = (float*)(ws + 5 * MB);             // 64 MB  [8][T][H] (aliases w1t+w3t; dead after gemm1_t2)
  unsigned short* w3t  = (unsigned short*)(ws + 37 * MB);   // 32 MB  [E][I][H]
  unsigned short* w2t  = (unsigned short*)(ws + 69 * MB);   // 32 MB  [E][H][I]
  unsigned short* hbuf = (unsigned short*)(ws + 101 * MB);  // 16 MB  [4096][I]

  gate_t13<<<4608, 256, 0, stream>>>(x, gw, gb, rec_e, rec_w, xb, w1, w3, w1t, w3t);
  route8<<<8, 256, 0, stream>>>(rec_e, rec_w, counts, list_tok, list_w);
  gemm1_t2<<<4096, 256, 0, stream>>>(xb, w1t, w3t, counts, list_tok, hbuf, w2, w2t);
  gemm2<<<dim3(H_DIM / 128, 64, E_NUM), 256, 0, stream>>>(hbuf, w2t, counts, list_tok, list_w, partial);
  combine8<<<(T_TOK * H_DIM) / (256 * 4), 256, 0, stream>>>(partial, out);
}